// Round 1
// baseline (5203.833 us; speedup 1.0000x reference)
//
#include <hip/hip_runtime.h>
#include <hip/hip_fp16.h>

// ---------------------------------------------------------------------------
// Sizes (fixed by the reference)
// ---------------------------------------------------------------------------
#define T_SEQ 4096
#define E_DIM 256
#define H_DIM 256
#define G3    768   // 3*H

// d_out layout (floats): [0,256) query | [256, 256+4095*256) keys | then med
#define KEYS_OFF 256
#define MED_OFF  1048576   // 256 + 4095*256

// ws layout (floats)
#define WS_SEQ_D   0
#define WS_SEQ_P   1048576            // 4096*256
#define WS_GI_D    2097152            // + 4096*256
#define WS_GI_P    5242880            // + 4096*768
#define WS_PATIENT 8388608            // + 4096*768   (patient: 4096*512)

typedef _Float16 h2 __attribute__((ext_vector_type(2)));

__device__ __forceinline__ float fdot2(h2 a, h2 b, float c) {
#if __has_builtin(__builtin_amdgcn_fdot2)
    return __builtin_amdgcn_fdot2(a, b, c, false);
#else
    return c + (float)a.x * (float)b.x + (float)a.y * (float)b.y;
#endif
}

__device__ __forceinline__ float fast_rcp(float x) {
#if __has_builtin(__builtin_amdgcn_rcpf)
    return __builtin_amdgcn_rcpf(x);
#else
    return 1.f / x;
#endif
}

// ---------------------------------------------------------------------------
// K1: embedding gather + mean (both seq_d and seq_p use emb_diag, per ref!)
//     also emits the int->float medication copy (independent output region)
// ---------------------------------------------------------------------------
__global__ __launch_bounds__(256) void gather_mean_kernel(
    const float* __restrict__ emb, const int* __restrict__ dcodes,
    const int* __restrict__ pcodes, const int* __restrict__ med,
    float* __restrict__ seq_d, float* __restrict__ seq_p,
    float* __restrict__ med_out)
{
    const int t = blockIdx.x;
    const int e = threadIdx.x;
    __shared__ int cd[32];
    __shared__ int cp[16];
    if (e < 32) cd[e] = dcodes[t * 32 + e];
    else if (e < 48) cp[e - 32] = pcodes[t * 16 + (e - 32)];
    __syncthreads();

    float sd = 0.f;
#pragma unroll 4
    for (int i = 0; i < 32; i++) sd += emb[(size_t)cd[i] * E_DIM + e];
    seq_d[(size_t)t * E_DIM + e] = sd * (1.f / 32.f);

    float sp = 0.f;
#pragma unroll 4
    for (int i = 0; i < 16; i++) sp += emb[(size_t)cp[i] * E_DIM + e];
    seq_p[(size_t)t * E_DIM + e] = sp * (1.f / 16.f);

    if (t < T_SEQ - 1 && e < 24) med_out[t * 24 + e] = (float)med[t * 24 + e];
}

// ---------------------------------------------------------------------------
// K2: gi = seq @ wih^T + bih, for both GRUs (blockIdx.z selects d/p)
//     M=4096, N=768, K=256.  BM=BN=128, BK=16, 256 thr, 8x8 micro-tile.
// ---------------------------------------------------------------------------
__global__ __launch_bounds__(256) void gemm_gi_kernel(
    const float* __restrict__ seq_d, const float* __restrict__ seq_p,
    const float* __restrict__ wih_d, const float* __restrict__ wih_p,
    const float* __restrict__ bih_d, const float* __restrict__ bih_p,
    float* __restrict__ gi_d, float* __restrict__ gi_p)
{
    const int K = E_DIM, N = G3;
    const float* A    = blockIdx.z ? seq_p : seq_d;
    const float* W    = blockIdx.z ? wih_p : wih_d;
    const float* bias = blockIdx.z ? bih_p : bih_d;
    float*       C    = blockIdx.z ? gi_p  : gi_d;

    __shared__ float As[16][132];
    __shared__ float Bs[16][132];

    const int tid = threadIdx.x;
    const int tx = tid & 15, ty = tid >> 4;
    const int m0 = blockIdx.x * 128, n0 = blockIdx.y * 128;
    const int r = tid >> 2;
    const int c = (tid & 3) << 2;

    float acc[8][8];
#pragma unroll
    for (int i = 0; i < 8; i++)
#pragma unroll
        for (int j = 0; j < 8; j++) acc[i][j] = 0.f;

    for (int k0 = 0; k0 < K; k0 += 16) {
        float4 a0 = *(const float4*)&A[(size_t)(m0 + r) * K + k0 + c];
        float4 a1 = *(const float4*)&A[(size_t)(m0 + r + 64) * K + k0 + c];
        float4 b0 = *(const float4*)&W[(size_t)(n0 + r) * K + k0 + c];
        float4 b1 = *(const float4*)&W[(size_t)(n0 + r + 64) * K + k0 + c];
        As[c + 0][r] = a0.x; As[c + 1][r] = a0.y; As[c + 2][r] = a0.z; As[c + 3][r] = a0.w;
        As[c + 0][r + 64] = a1.x; As[c + 1][r + 64] = a1.y; As[c + 2][r + 64] = a1.z; As[c + 3][r + 64] = a1.w;
        Bs[c + 0][r] = b0.x; Bs[c + 1][r] = b0.y; Bs[c + 2][r] = b0.z; Bs[c + 3][r] = b0.w;
        Bs[c + 0][r + 64] = b1.x; Bs[c + 1][r + 64] = b1.y; Bs[c + 2][r + 64] = b1.z; Bs[c + 3][r + 64] = b1.w;
        __syncthreads();
#pragma unroll
        for (int k = 0; k < 16; k++) {
            float4 aa0 = *(const float4*)&As[k][ty * 8];
            float4 aa1 = *(const float4*)&As[k][ty * 8 + 4];
            float4 bb0 = *(const float4*)&Bs[k][tx * 8];
            float4 bb1 = *(const float4*)&Bs[k][tx * 8 + 4];
            float a[8] = {aa0.x, aa0.y, aa0.z, aa0.w, aa1.x, aa1.y, aa1.z, aa1.w};
            float b[8] = {bb0.x, bb0.y, bb0.z, bb0.w, bb1.x, bb1.y, bb1.z, bb1.w};
#pragma unroll
            for (int i = 0; i < 8; i++)
#pragma unroll
                for (int j = 0; j < 8; j++) acc[i][j] = fmaf(a[i], b[j], acc[i][j]);
        }
        __syncthreads();
    }

#pragma unroll
    for (int i = 0; i < 8; i++) {
        const int m = m0 + ty * 8 + i;
#pragma unroll
        for (int j = 0; j < 8; j++) {
            const int n = n0 + tx * 8 + j;
            C[(size_t)m * N + n] = acc[i][j] + bias[n];
        }
    }
}

// ---------------------------------------------------------------------------
// K3: the sequential GRU scans.  grid=2 (block 0 = diag, block 1 = proc),
//     1024 threads.  whh register-resident as f16 (96 VGPRs of weights).
//     quad (4 lanes) owns hidden dim q = tid>>2; lane l=tid&3 covers
//     k in [l*64, l*64+64).  96 v_dot2_f32_f16 per thread per step.
// ---------------------------------------------------------------------------
__global__ __launch_bounds__(1024) void gru_scan_kernel(
    const float* __restrict__ whh_d, const float* __restrict__ whh_p,
    const float* __restrict__ bhh_d, const float* __restrict__ bhh_p,
    const float* __restrict__ gi_d, const float* __restrict__ gi_p,
    float* __restrict__ patient)
{
    const float* whh = blockIdx.x ? whh_p : whh_d;
    const float* bhh = blockIdx.x ? bhh_p : bhh_d;
    const float* gi  = blockIdx.x ? gi_p  : gi_d;
    const int col_off = blockIdx.x ? H_DIM : 0;

    const int tid = threadIdx.x;
    const int q = tid >> 2;
    const int l = tid & 3;

    // --- load + convert weights into registers: w[g][p] covers k-dims
    //     (l*64 + 2p, l*64 + 2p + 1) of output row g*256+q ---
    h2 w[3][32];
#pragma unroll
    for (int g = 0; g < 3; g++) {
        const float4* p = (const float4*)(whh + (size_t)(g * 256 + q) * H_DIM + l * 64);
#pragma unroll
        for (int i = 0; i < 16; i++) {
            float4 f = p[i];
            h2 v0; v0.x = (_Float16)f.x; v0.y = (_Float16)f.y;
            h2 v1; v1.x = (_Float16)f.z; v1.y = (_Float16)f.w;
            w[g][2 * i] = v0;
            w[g][2 * i + 1] = v1;
        }
    }
    const float b0 = bhh[q], b1 = bhh[256 + q], b2 = bhh[512 + q];

    __shared__ __align__(16) _Float16 hb[2][H_DIM];
    if (tid < H_DIM) hb[0][tid] = (_Float16)0.f;

    float h = 0.f, g0 = 0.f, g1 = 0.f, g2 = 0.f;
    if (l == 0) { g0 = gi[q]; g1 = gi[256 + q]; g2 = gi[512 + q]; }
    __syncthreads();

    for (int t = 0; t < T_SEQ; t++) {
        const uint4* hp = (const uint4*)(&hb[t & 1][l << 6]);
        float a0 = 0.f, a1 = 0.f, a2 = 0.f;
#pragma unroll
        for (int cI = 0; cI < 8; cI++) {
            const uint4 U = hp[cI];
            const h2 x0 = __builtin_bit_cast(h2, U.x);
            const h2 x1 = __builtin_bit_cast(h2, U.y);
            const h2 x2 = __builtin_bit_cast(h2, U.z);
            const h2 x3 = __builtin_bit_cast(h2, U.w);
            a0 = fdot2(w[0][4 * cI + 0], x0, a0);
            a0 = fdot2(w[0][4 * cI + 1], x1, a0);
            a0 = fdot2(w[0][4 * cI + 2], x2, a0);
            a0 = fdot2(w[0][4 * cI + 3], x3, a0);
            a1 = fdot2(w[1][4 * cI + 0], x0, a1);
            a1 = fdot2(w[1][4 * cI + 1], x1, a1);
            a1 = fdot2(w[1][4 * cI + 2], x2, a1);
            a1 = fdot2(w[1][4 * cI + 3], x3, a1);
            a2 = fdot2(w[2][4 * cI + 0], x0, a2);
            a2 = fdot2(w[2][4 * cI + 1], x1, a2);
            a2 = fdot2(w[2][4 * cI + 2], x2, a2);
            a2 = fdot2(w[2][4 * cI + 3], x3, a2);
        }
        // quad reduction (lanes l=0..3 are consecutive)
        a0 += __shfl_xor(a0, 1); a0 += __shfl_xor(a0, 2);
        a1 += __shfl_xor(a1, 1); a1 += __shfl_xor(a1, 2);
        a2 += __shfl_xor(a2, 1); a2 += __shfl_xor(a2, 2);

        if (l == 0) {
            const float xr = g0 + a0 + b0;
            const float xz = g1 + a1 + b1;
            const float r = fast_rcp(1.f + __expf(-xr));
            const float z = fast_rcp(1.f + __expf(-xz));
            float xn = g2 + r * (a2 + b2);
            xn = fminf(fmaxf(xn, -15.f), 15.f);
            const float e2 = __expf(2.f * xn);
            const float n = (e2 - 1.f) * fast_rcp(e2 + 1.f);
            h = (1.f - z) * n + z * h;
            hb[(t + 1) & 1][q] = (_Float16)h;
            patient[(size_t)t * 512 + col_off + q] = h;
            const int tn = (t < T_SEQ - 1) ? (t + 1) : t;   // prefetch next gi
            g0 = gi[(size_t)tn * G3 + q];
            g1 = gi[(size_t)tn * G3 + 256 + q];
            g2 = gi[(size_t)tn * G3 + 512 + q];
        }
        __syncthreads();
    }
}

// ---------------------------------------------------------------------------
// K4: queries = relu(patient) @ w_lin^T + b_lin, scattered into d_out:
//     row 4095 -> query region [0,256); rows 0..4094 -> keys region.
//     M=4096, N=256, K=512.
// ---------------------------------------------------------------------------
__global__ __launch_bounds__(256) void gemm_fin_kernel(
    const float* __restrict__ patient, const float* __restrict__ w_lin,
    const float* __restrict__ b_lin, float* __restrict__ out)
{
    const int K = 512, N = H_DIM;

    __shared__ float As[16][132];
    __shared__ float Bs[16][132];

    const int tid = threadIdx.x;
    const int tx = tid & 15, ty = tid >> 4;
    const int m0 = blockIdx.x * 128, n0 = blockIdx.y * 128;
    const int r = tid >> 2;
    const int c = (tid & 3) << 2;

    float acc[8][8];
#pragma unroll
    for (int i = 0; i < 8; i++)
#pragma unroll
        for (int j = 0; j < 8; j++) acc[i][j] = 0.f;

    for (int k0 = 0; k0 < K; k0 += 16) {
        float4 a0 = *(const float4*)&patient[(size_t)(m0 + r) * K + k0 + c];
        float4 a1 = *(const float4*)&patient[(size_t)(m0 + r + 64) * K + k0 + c];
        float4 b0 = *(const float4*)&w_lin[(size_t)(n0 + r) * K + k0 + c];
        float4 b1 = *(const float4*)&w_lin[(size_t)(n0 + r + 64) * K + k0 + c];
        // relu on A
        a0.x = fmaxf(a0.x, 0.f); a0.y = fmaxf(a0.y, 0.f); a0.z = fmaxf(a0.z, 0.f); a0.w = fmaxf(a0.w, 0.f);
        a1.x = fmaxf(a1.x, 0.f); a1.y = fmaxf(a1.y, 0.f); a1.z = fmaxf(a1.z, 0.f); a1.w = fmaxf(a1.w, 0.f);
        As[c + 0][r] = a0.x; As[c + 1][r] = a0.y; As[c + 2][r] = a0.z; As[c + 3][r] = a0.w;
        As[c + 0][r + 64] = a1.x; As[c + 1][r + 64] = a1.y; As[c + 2][r + 64] = a1.z; As[c + 3][r + 64] = a1.w;
        Bs[c + 0][r] = b0.x; Bs[c + 1][r] = b0.y; Bs[c + 2][r] = b0.z; Bs[c + 3][r] = b0.w;
        Bs[c + 0][r + 64] = b1.x; Bs[c + 1][r + 64] = b1.y; Bs[c + 2][r + 64] = b1.z; Bs[c + 3][r + 64] = b1.w;
        __syncthreads();
#pragma unroll
        for (int k = 0; k < 16; k++) {
            float4 aa0 = *(const float4*)&As[k][ty * 8];
            float4 aa1 = *(const float4*)&As[k][ty * 8 + 4];
            float4 bb0 = *(const float4*)&Bs[k][tx * 8];
            float4 bb1 = *(const float4*)&Bs[k][tx * 8 + 4];
            float a[8] = {aa0.x, aa0.y, aa0.z, aa0.w, aa1.x, aa1.y, aa1.z, aa1.w};
            float b[8] = {bb0.x, bb0.y, bb0.z, bb0.w, bb1.x, bb1.y, bb1.z, bb1.w};
#pragma unroll
            for (int i = 0; i < 8; i++)
#pragma unroll
                for (int j = 0; j < 8; j++) acc[i][j] = fmaf(a[i], b[j], acc[i][j]);
        }
        __syncthreads();
    }

#pragma unroll
    for (int i = 0; i < 8; i++) {
        const int m = m0 + ty * 8 + i;
#pragma unroll
        for (int j = 0; j < 8; j++) {
            const int n = n0 + tx * 8 + j;
            const float v = acc[i][j] + b_lin[n];
            if (m == T_SEQ - 1) out[n] = v;                       // query
            else out[KEYS_OFF + (size_t)m * H_DIM + n] = v;       // memory_keys
        }
    }
}

// ---------------------------------------------------------------------------
extern "C" void kernel_launch(void* const* d_in, const int* in_sizes, int n_in,
                              void* d_out, int out_size, void* d_ws, size_t ws_size,
                              hipStream_t stream)
{
    const float* emb_diag = (const float*)d_in[0];
    // d_in[1] (emb_proc) is unused by the reference.
    const float* wih_d = (const float*)d_in[2];
    const float* whh_d = (const float*)d_in[3];
    const float* bih_d = (const float*)d_in[4];
    const float* bhh_d = (const float*)d_in[5];
    const float* wih_p = (const float*)d_in[6];
    const float* whh_p = (const float*)d_in[7];
    const float* bih_p = (const float*)d_in[8];
    const float* bhh_p = (const float*)d_in[9];
    const float* w_lin = (const float*)d_in[10];
    const float* b_lin = (const float*)d_in[11];
    const int* dcodes = (const int*)d_in[12];
    const int* pcodes = (const int*)d_in[13];
    const int* med    = (const int*)d_in[14];

    float* out = (float*)d_out;
    float* ws  = (float*)d_ws;

    float* seq_d   = ws + WS_SEQ_D;
    float* seq_p   = ws + WS_SEQ_P;
    float* gi_d    = ws + WS_GI_D;
    float* gi_p    = ws + WS_GI_P;
    float* patient = ws + WS_PATIENT;

    gather_mean_kernel<<<T_SEQ, 256, 0, stream>>>(
        emb_diag, dcodes, pcodes, med, seq_d, seq_p, out + MED_OFF);

    gemm_gi_kernel<<<dim3(32, 6, 2), 256, 0, stream>>>(
        seq_d, seq_p, wih_d, wih_p, bih_d, bih_p, gi_d, gi_p);

    gru_scan_kernel<<<2, 1024, 0, stream>>>(
        whh_d, whh_p, bhh_d, bhh_p, gi_d, gi_p, patient);

    gemm_fin_kernel<<<dim3(32, 2, 1), 256, 0, stream>>>(
        patient, w_lin, b_lin, out);
}

// Round 2
// 4985.741 us; speedup vs baseline: 1.0437x; 1.0437x over previous
//
#include <hip/hip_runtime.h>
#include <hip/hip_fp16.h>

// ---------------------------------------------------------------------------
// Sizes (fixed by the reference)
// ---------------------------------------------------------------------------
#define T_SEQ 4096
#define E_DIM 256
#define H_DIM 256
#define G3    768   // 3*H

// d_out layout (floats): [0,256) query | [256, 256+4095*256) keys | then med
#define KEYS_OFF 256
#define MED_OFF  1048576   // 256 + 4095*256

// ws layout (floats)
#define WS_SEQ_D   0
#define WS_SEQ_P   1048576            // 4096*256
#define WS_GI_D    2097152            // + 4096*256
#define WS_GI_P    5242880            // + 4096*768
#define WS_PATIENT 8388608            // + 4096*768   (patient: 4096*512)

typedef _Float16 h2 __attribute__((ext_vector_type(2)));

__device__ __forceinline__ float fdot2(h2 a, h2 b, float c) {
#if __has_builtin(__builtin_amdgcn_fdot2)
    return __builtin_amdgcn_fdot2(a, b, c, false);
#else
    return c + (float)a.x * (float)b.x + (float)a.y * (float)b.y;
#endif
}

__device__ __forceinline__ float fast_rcp(float x) {
#if __has_builtin(__builtin_amdgcn_rcpf)
    return __builtin_amdgcn_rcpf(x);
#else
    return 1.f / x;
#endif
}

// Sum across a quad (lanes l, l^1, l^2 consecutive) using pure-VALU DPP
// quad_perm — avoids ds_swizzle (LDS unit) that __shfl_xor may lower to.
__device__ __forceinline__ float quad_sum(float x) {
#if __has_builtin(__builtin_amdgcn_update_dpp)
    int y1 = __builtin_amdgcn_update_dpp(0, __builtin_bit_cast(int, x),
                                         0xB1 /*quad_perm [1,0,3,2]*/, 0xF, 0xF, true);
    x += __builtin_bit_cast(float, y1);
    int y2 = __builtin_amdgcn_update_dpp(0, __builtin_bit_cast(int, x),
                                         0x4E /*quad_perm [2,3,0,1]*/, 0xF, 0xF, true);
    x += __builtin_bit_cast(float, y2);
    return x;
#else
    x += __shfl_xor(x, 1);
    x += __shfl_xor(x, 2);
    return x;
#endif
}

// ---------------------------------------------------------------------------
// K1: embedding gather + mean (both seq_d and seq_p use emb_diag, per ref!)
//     also emits the int->float medication copy (independent output region)
// ---------------------------------------------------------------------------
__global__ __launch_bounds__(256) void gather_mean_kernel(
    const float* __restrict__ emb, const int* __restrict__ dcodes,
    const int* __restrict__ pcodes, const int* __restrict__ med,
    float* __restrict__ seq_d, float* __restrict__ seq_p,
    float* __restrict__ med_out)
{
    const int t = blockIdx.x;
    const int e = threadIdx.x;
    __shared__ int cd[32];
    __shared__ int cp[16];
    if (e < 32) cd[e] = dcodes[t * 32 + e];
    else if (e < 48) cp[e - 32] = pcodes[t * 16 + (e - 32)];
    __syncthreads();

    float sd = 0.f;
#pragma unroll 4
    for (int i = 0; i < 32; i++) sd += emb[(size_t)cd[i] * E_DIM + e];
    seq_d[(size_t)t * E_DIM + e] = sd * (1.f / 32.f);

    float sp = 0.f;
#pragma unroll 4
    for (int i = 0; i < 16; i++) sp += emb[(size_t)cp[i] * E_DIM + e];
    seq_p[(size_t)t * E_DIM + e] = sp * (1.f / 16.f);

    if (t < T_SEQ - 1 && e < 24) med_out[t * 24 + e] = (float)med[t * 24 + e];
}

// ---------------------------------------------------------------------------
// K2: gi = seq @ wih^T + bih, for both GRUs (blockIdx.z selects d/p)
//     M=4096, N=768, K=256.  BM=BN=128, BK=16, 256 thr, 8x8 micro-tile.
// ---------------------------------------------------------------------------
__global__ __launch_bounds__(256) void gemm_gi_kernel(
    const float* __restrict__ seq_d, const float* __restrict__ seq_p,
    const float* __restrict__ wih_d, const float* __restrict__ wih_p,
    const float* __restrict__ bih_d, const float* __restrict__ bih_p,
    float* __restrict__ gi_d, float* __restrict__ gi_p)
{
    const int K = E_DIM, N = G3;
    const float* A    = blockIdx.z ? seq_p : seq_d;
    const float* W    = blockIdx.z ? wih_p : wih_d;
    const float* bias = blockIdx.z ? bih_p : bih_d;
    float*       C    = blockIdx.z ? gi_p  : gi_d;

    __shared__ float As[16][132];
    __shared__ float Bs[16][132];

    const int tid = threadIdx.x;
    const int tx = tid & 15, ty = tid >> 4;
    const int m0 = blockIdx.x * 128, n0 = blockIdx.y * 128;
    const int r = tid >> 2;
    const int c = (tid & 3) << 2;

    float acc[8][8];
#pragma unroll
    for (int i = 0; i < 8; i++)
#pragma unroll
        for (int j = 0; j < 8; j++) acc[i][j] = 0.f;

    for (int k0 = 0; k0 < K; k0 += 16) {
        float4 a0 = *(const float4*)&A[(size_t)(m0 + r) * K + k0 + c];
        float4 a1 = *(const float4*)&A[(size_t)(m0 + r + 64) * K + k0 + c];
        float4 b0 = *(const float4*)&W[(size_t)(n0 + r) * K + k0 + c];
        float4 b1 = *(const float4*)&W[(size_t)(n0 + r + 64) * K + k0 + c];
        As[c + 0][r] = a0.x; As[c + 1][r] = a0.y; As[c + 2][r] = a0.z; As[c + 3][r] = a0.w;
        As[c + 0][r + 64] = a1.x; As[c + 1][r + 64] = a1.y; As[c + 2][r + 64] = a1.z; As[c + 3][r + 64] = a1.w;
        Bs[c + 0][r] = b0.x; Bs[c + 1][r] = b0.y; Bs[c + 2][r] = b0.z; Bs[c + 3][r] = b0.w;
        Bs[c + 0][r + 64] = b1.x; Bs[c + 1][r + 64] = b1.y; Bs[c + 2][r + 64] = b1.z; Bs[c + 3][r + 64] = b1.w;
        __syncthreads();
#pragma unroll
        for (int k = 0; k < 16; k++) {
            float4 aa0 = *(const float4*)&As[k][ty * 8];
            float4 aa1 = *(const float4*)&As[k][ty * 8 + 4];
            float4 bb0 = *(const float4*)&Bs[k][tx * 8];
            float4 bb1 = *(const float4*)&Bs[k][tx * 8 + 4];
            float a[8] = {aa0.x, aa0.y, aa0.z, aa0.w, aa1.x, aa1.y, aa1.z, aa1.w};
            float b[8] = {bb0.x, bb0.y, bb0.z, bb0.w, bb1.x, bb1.y, bb1.z, bb1.w};
#pragma unroll
            for (int i = 0; i < 8; i++)
#pragma unroll
                for (int j = 0; j < 8; j++) acc[i][j] = fmaf(a[i], b[j], acc[i][j]);
        }
        __syncthreads();
    }

#pragma unroll
    for (int i = 0; i < 8; i++) {
        const int m = m0 + ty * 8 + i;
#pragma unroll
        for (int j = 0; j < 8; j++) {
            const int n = n0 + tx * 8 + j;
            C[(size_t)m * N + n] = acc[i][j] + bias[n];
        }
    }
}

// ---------------------------------------------------------------------------
// K3: the sequential GRU scans.  grid=2 (block 0 = diag, block 1 = proc),
//     1024 threads.  __launch_bounds__(1024, 4) => 128-VGPR budget so the
//     96 VGPRs of f16 whh weights stay in *architectural* VGPRs (round-1
//     showed VGPR_Count=64 => AGPR/scratch shuttling, ~2.5x VALU inflation).
//     quad (4 lanes) owns hidden dim q = tid>>2; lane l=tid&3 covers
//     k in [l*64, l*64+64).  96 v_dot2_f32_f16 per thread per step.
//     h buffer: 4 chunks of 64 f16 padded to 72 f16 (stride 144 B) so the 4
//     distinct ds_read_b128 addresses land in banks {4l..4l+3} (round-1:
//     4-way conflict on banks 0-3, 4.2M conflict cycles).
// ---------------------------------------------------------------------------
#define HB_STRIDE 72   // 64 f16 payload + 8 f16 pad = 144 B

__global__ __launch_bounds__(1024, 4) void gru_scan_kernel(
    const float* __restrict__ whh_d, const float* __restrict__ whh_p,
    const float* __restrict__ bhh_d, const float* __restrict__ bhh_p,
    const float* __restrict__ gi_d, const float* __restrict__ gi_p,
    float* __restrict__ patient)
{
    const float* whh = blockIdx.x ? whh_p : whh_d;
    const float* bhh = blockIdx.x ? bhh_p : bhh_d;
    const float* gi  = blockIdx.x ? gi_p  : gi_d;
    const int col_off = blockIdx.x ? H_DIM : 0;

    const int tid = threadIdx.x;
    const int q = tid >> 2;
    const int l = tid & 3;

    // --- load + convert weights into registers: w[g][p] covers k-dims
    //     (l*64 + 2p, l*64 + 2p + 1) of output row g*256+q ---
    h2 w[3][32];
#pragma unroll
    for (int g = 0; g < 3; g++) {
        const float4* p = (const float4*)(whh + (size_t)(g * 256 + q) * H_DIM + l * 64);
#pragma unroll
        for (int i = 0; i < 16; i++) {
            float4 f = p[i];
            h2 v0; v0.x = (_Float16)f.x; v0.y = (_Float16)f.y;
            h2 v1; v1.x = (_Float16)f.z; v1.y = (_Float16)f.w;
            w[g][2 * i] = v0;
            w[g][2 * i + 1] = v1;
        }
    }
    const float b0 = bhh[q], b1 = bhh[256 + q], b2 = bhh[512 + q];

    __shared__ __align__(16) _Float16 hb[2][4 * HB_STRIDE];
    if (tid < 4 * HB_STRIDE) hb[0][tid] = (_Float16)0.f;

    float h = 0.f, g0 = 0.f, g1 = 0.f, g2 = 0.f;
    if (l == 0) { g0 = gi[q]; g1 = gi[256 + q]; g2 = gi[512 + q]; }
    __syncthreads();

    for (int t = 0; t < T_SEQ; t++) {
        const uint4* hp = (const uint4*)(&hb[t & 1][l * HB_STRIDE]);
        float a0 = 0.f, a1 = 0.f, a2 = 0.f;
#pragma unroll
        for (int cI = 0; cI < 8; cI++) {
            const uint4 U = hp[cI];
            const h2 x0 = __builtin_bit_cast(h2, U.x);
            const h2 x1 = __builtin_bit_cast(h2, U.y);
            const h2 x2 = __builtin_bit_cast(h2, U.z);
            const h2 x3 = __builtin_bit_cast(h2, U.w);
            a0 = fdot2(w[0][4 * cI + 0], x0, a0);
            a0 = fdot2(w[0][4 * cI + 1], x1, a0);
            a0 = fdot2(w[0][4 * cI + 2], x2, a0);
            a0 = fdot2(w[0][4 * cI + 3], x3, a0);
            a1 = fdot2(w[1][4 * cI + 0], x0, a1);
            a1 = fdot2(w[1][4 * cI + 1], x1, a1);
            a1 = fdot2(w[1][4 * cI + 2], x2, a1);
            a1 = fdot2(w[1][4 * cI + 3], x3, a1);
            a2 = fdot2(w[2][4 * cI + 0], x0, a2);
            a2 = fdot2(w[2][4 * cI + 1], x1, a2);
            a2 = fdot2(w[2][4 * cI + 2], x2, a2);
            a2 = fdot2(w[2][4 * cI + 3], x3, a2);
        }
        // quad reduction (pure-VALU DPP)
        a0 = quad_sum(a0);
        a1 = quad_sum(a1);
        a2 = quad_sum(a2);

        if (l == 0) {
            const float xr = g0 + a0 + b0;
            const float xz = g1 + a1 + b1;
            const float r = fast_rcp(1.f + __expf(-xr));
            const float z = fast_rcp(1.f + __expf(-xz));
            float xn = g2 + r * (a2 + b2);
            xn = fminf(fmaxf(xn, -15.f), 15.f);
            const float e2 = __expf(2.f * xn);
            const float n = (e2 - 1.f) * fast_rcp(e2 + 1.f);
            h = (1.f - z) * n + z * h;
            hb[(t + 1) & 1][(q >> 6) * HB_STRIDE + (q & 63)] = (_Float16)h;
            patient[(size_t)t * 512 + col_off + q] = h;
            const int tn = (t < T_SEQ - 1) ? (t + 1) : t;   // prefetch next gi
            g0 = gi[(size_t)tn * G3 + q];
            g1 = gi[(size_t)tn * G3 + 256 + q];
            g2 = gi[(size_t)tn * G3 + 512 + q];
        }
        __syncthreads();
    }
}

// ---------------------------------------------------------------------------
// K4: queries = relu(patient) @ w_lin^T + b_lin, scattered into d_out:
//     row 4095 -> query region [0,256); rows 0..4094 -> keys region.
//     M=4096, N=256, K=512.
// ---------------------------------------------------------------------------
__global__ __launch_bounds__(256) void gemm_fin_kernel(
    const float* __restrict__ patient, const float* __restrict__ w_lin,
    const float* __restrict__ b_lin, float* __restrict__ out)
{
    const int K = 512, N = H_DIM;

    __shared__ float As[16][132];
    __shared__ float Bs[16][132];

    const int tid = threadIdx.x;
    const int tx = tid & 15, ty = tid >> 4;
    const int m0 = blockIdx.x * 128, n0 = blockIdx.y * 128;
    const int r = tid >> 2;
    const int c = (tid & 3) << 2;

    float acc[8][8];
#pragma unroll
    for (int i = 0; i < 8; i++)
#pragma unroll
        for (int j = 0; j < 8; j++) acc[i][j] = 0.f;

    for (int k0 = 0; k0 < K; k0 += 16) {
        float4 a0 = *(const float4*)&patient[(size_t)(m0 + r) * K + k0 + c];
        float4 a1 = *(const float4*)&patient[(size_t)(m0 + r + 64) * K + k0 + c];
        float4 b0 = *(const float4*)&w_lin[(size_t)(n0 + r) * K + k0 + c];
        float4 b1 = *(const float4*)&w_lin[(size_t)(n0 + r + 64) * K + k0 + c];
        // relu on A
        a0.x = fmaxf(a0.x, 0.f); a0.y = fmaxf(a0.y, 0.f); a0.z = fmaxf(a0.z, 0.f); a0.w = fmaxf(a0.w, 0.f);
        a1.x = fmaxf(a1.x, 0.f); a1.y = fmaxf(a1.y, 0.f); a1.z = fmaxf(a1.z, 0.f); a1.w = fmaxf(a1.w, 0.f);
        As[c + 0][r] = a0.x; As[c + 1][r] = a0.y; As[c + 2][r] = a0.z; As[c + 3][r] = a0.w;
        As[c + 0][r + 64] = a1.x; As[c + 1][r + 64] = a1.y; As[c + 2][r + 64] = a1.z; As[c + 3][r + 64] = a1.w;
        Bs[c + 0][r] = b0.x; Bs[c + 1][r] = b0.y; Bs[c + 2][r] = b0.z; Bs[c + 3][r] = b0.w;
        Bs[c + 0][r + 64] = b1.x; Bs[c + 1][r + 64] = b1.y; Bs[c + 2][r + 64] = b1.z; Bs[c + 3][r + 64] = b1.w;
        __syncthreads();
#pragma unroll
        for (int k = 0; k < 16; k++) {
            float4 aa0 = *(const float4*)&As[k][ty * 8];
            float4 aa1 = *(const float4*)&As[k][ty * 8 + 4];
            float4 bb0 = *(const float4*)&Bs[k][tx * 8];
            float4 bb1 = *(const float4*)&Bs[k][tx * 8 + 4];
            float a[8] = {aa0.x, aa0.y, aa0.z, aa0.w, aa1.x, aa1.y, aa1.z, aa1.w};
            float b[8] = {bb0.x, bb0.y, bb0.z, bb0.w, bb1.x, bb1.y, bb1.z, bb1.w};
#pragma unroll
            for (int i = 0; i < 8; i++)
#pragma unroll
                for (int j = 0; j < 8; j++) acc[i][j] = fmaf(a[i], b[j], acc[i][j]);
        }
        __syncthreads();
    }

#pragma unroll
    for (int i = 0; i < 8; i++) {
        const int m = m0 + ty * 8 + i;
#pragma unroll
        for (int j = 0; j < 8; j++) {
            const int n = n0 + tx * 8 + j;
            const float v = acc[i][j] + b_lin[n];
            if (m == T_SEQ - 1) out[n] = v;                       // query
            else out[KEYS_OFF + (size_t)m * H_DIM + n] = v;       // memory_keys
        }
    }
}

// ---------------------------------------------------------------------------
extern "C" void kernel_launch(void* const* d_in, const int* in_sizes, int n_in,
                              void* d_out, int out_size, void* d_ws, size_t ws_size,
                              hipStream_t stream)
{
    const float* emb_diag = (const float*)d_in[0];
    // d_in[1] (emb_proc) is unused by the reference.
    const float* wih_d = (const float*)d_in[2];
    const float* whh_d = (const float*)d_in[3];
    const float* bih_d = (const float*)d_in[4];
    const float* bhh_d = (const float*)d_in[5];
    const float* wih_p = (const float*)d_in[6];
    const float* whh_p = (const float*)d_in[7];
    const float* bih_p = (const float*)d_in[8];
    const float* bhh_p = (const float*)d_in[9];
    const float* w_lin = (const float*)d_in[10];
    const float* b_lin = (const float*)d_in[11];
    const int* dcodes = (const int*)d_in[12];
    const int* pcodes = (const int*)d_in[13];
    const int* med    = (const int*)d_in[14];

    float* out = (float*)d_out;
    float* ws  = (float*)d_ws;

    float* seq_d   = ws + WS_SEQ_D;
    float* seq_p   = ws + WS_SEQ_P;
    float* gi_d    = ws + WS_GI_D;
    float* gi_p    = ws + WS_GI_P;
    float* patient = ws + WS_PATIENT;

    gather_mean_kernel<<<T_SEQ, 256, 0, stream>>>(
        emb_diag, dcodes, pcodes, med, seq_d, seq_p, out + MED_OFF);

    gemm_gi_kernel<<<dim3(32, 6, 2), 256, 0, stream>>>(
        seq_d, seq_p, wih_d, wih_p, bih_d, bih_p, gi_d, gi_p);

    gru_scan_kernel<<<2, 1024, 0, stream>>>(
        whh_d, whh_p, bhh_d, bhh_p, gi_d, gi_p, patient);

    gemm_fin_kernel<<<dim3(32, 2, 1), 256, 0, stream>>>(
        patient, w_lin, b_lin, out);
}

// Round 3
// 4395.311 us; speedup vs baseline: 1.1840x; 1.1343x over previous
//
#include <hip/hip_runtime.h>
#include <hip/hip_fp16.h>

// ---------------------------------------------------------------------------
// Sizes (fixed by the reference)
// ---------------------------------------------------------------------------
#define T_SEQ 4096
#define E_DIM 256
#define H_DIM 256
#define G3    768   // 3*H

// d_out layout (floats): [0,256) query | [256, 256+4095*256) keys | then med
#define KEYS_OFF 256
#define MED_OFF  1048576   // 256 + 4095*256

// ws layout (floats)
#define WS_SEQ_D   0
#define WS_SEQ_P   1048576            // 4096*256
#define WS_GI_D    2097152            // + 4096*256
#define WS_GI_P    5242880            // + 4096*768
#define WS_PATIENT 8388608            // + 4096*768   (patient: 4096*512)

typedef _Float16 h2 __attribute__((ext_vector_type(2)));

__device__ __forceinline__ float fdot2(h2 a, h2 b, float c) {
#if __has_builtin(__builtin_amdgcn_fdot2)
    return __builtin_amdgcn_fdot2(a, b, c, false);
#else
    return c + (float)a.x * (float)b.x + (float)a.y * (float)b.y;
#endif
}

__device__ __forceinline__ float fast_rcp(float x) {
#if __has_builtin(__builtin_amdgcn_rcpf)
    return __builtin_amdgcn_rcpf(x);
#else
    return 1.f / x;
#endif
}

// Sum across a quad (lanes l, l^1, l^2 consecutive) using pure-VALU DPP.
__device__ __forceinline__ float quad_sum(float x) {
#if __has_builtin(__builtin_amdgcn_update_dpp)
    int y1 = __builtin_amdgcn_update_dpp(0, __builtin_bit_cast(int, x),
                                         0xB1 /*quad_perm [1,0,3,2]*/, 0xF, 0xF, true);
    x += __builtin_bit_cast(float, y1);
    int y2 = __builtin_amdgcn_update_dpp(0, __builtin_bit_cast(int, x),
                                         0x4E /*quad_perm [2,3,0,1]*/, 0xF, 0xF, true);
    x += __builtin_bit_cast(float, y2);
    return x;
#else
    x += __shfl_xor(x, 1);
    x += __shfl_xor(x, 2);
    return x;
#endif
}

// ---------------------------------------------------------------------------
// K1: embedding gather + mean (both seq_d and seq_p use emb_diag, per ref!)
// ---------------------------------------------------------------------------
__global__ __launch_bounds__(256) void gather_mean_kernel(
    const float* __restrict__ emb, const int* __restrict__ dcodes,
    const int* __restrict__ pcodes, const int* __restrict__ med,
    float* __restrict__ seq_d, float* __restrict__ seq_p,
    float* __restrict__ med_out)
{
    const int t = blockIdx.x;
    const int e = threadIdx.x;
    __shared__ int cd[32];
    __shared__ int cp[16];
    if (e < 32) cd[e] = dcodes[t * 32 + e];
    else if (e < 48) cp[e - 32] = pcodes[t * 16 + (e - 32)];
    __syncthreads();

    float sd = 0.f;
#pragma unroll 4
    for (int i = 0; i < 32; i++) sd += emb[(size_t)cd[i] * E_DIM + e];
    seq_d[(size_t)t * E_DIM + e] = sd * (1.f / 32.f);

    float sp = 0.f;
#pragma unroll 4
    for (int i = 0; i < 16; i++) sp += emb[(size_t)cp[i] * E_DIM + e];
    seq_p[(size_t)t * E_DIM + e] = sp * (1.f / 16.f);

    if (t < T_SEQ - 1 && e < 24) med_out[t * 24 + e] = (float)med[t * 24 + e];
}

// ---------------------------------------------------------------------------
// K2: gi = seq @ wih^T + bih, for both GRUs (blockIdx.z selects d/p)
// ---------------------------------------------------------------------------
__global__ __launch_bounds__(256) void gemm_gi_kernel(
    const float* __restrict__ seq_d, const float* __restrict__ seq_p,
    const float* __restrict__ wih_d, const float* __restrict__ wih_p,
    const float* __restrict__ bih_d, const float* __restrict__ bih_p,
    float* __restrict__ gi_d, float* __restrict__ gi_p)
{
    const int K = E_DIM, N = G3;
    const float* A    = blockIdx.z ? seq_p : seq_d;
    const float* W    = blockIdx.z ? wih_p : wih_d;
    const float* bias = blockIdx.z ? bih_p : bih_d;
    float*       C    = blockIdx.z ? gi_p  : gi_d;

    __shared__ float As[16][132];
    __shared__ float Bs[16][132];

    const int tid = threadIdx.x;
    const int tx = tid & 15, ty = tid >> 4;
    const int m0 = blockIdx.x * 128, n0 = blockIdx.y * 128;
    const int r = tid >> 2;
    const int c = (tid & 3) << 2;

    float acc[8][8];
#pragma unroll
    for (int i = 0; i < 8; i++)
#pragma unroll
        for (int j = 0; j < 8; j++) acc[i][j] = 0.f;

    for (int k0 = 0; k0 < K; k0 += 16) {
        float4 a0 = *(const float4*)&A[(size_t)(m0 + r) * K + k0 + c];
        float4 a1 = *(const float4*)&A[(size_t)(m0 + r + 64) * K + k0 + c];
        float4 b0 = *(const float4*)&W[(size_t)(n0 + r) * K + k0 + c];
        float4 b1 = *(const float4*)&W[(size_t)(n0 + r + 64) * K + k0 + c];
        As[c + 0][r] = a0.x; As[c + 1][r] = a0.y; As[c + 2][r] = a0.z; As[c + 3][r] = a0.w;
        As[c + 0][r + 64] = a1.x; As[c + 1][r + 64] = a1.y; As[c + 2][r + 64] = a1.z; As[c + 3][r + 64] = a1.w;
        Bs[c + 0][r] = b0.x; Bs[c + 1][r] = b0.y; Bs[c + 2][r] = b0.z; Bs[c + 3][r] = b0.w;
        Bs[c + 0][r + 64] = b1.x; Bs[c + 1][r + 64] = b1.y; Bs[c + 2][r + 64] = b1.z; Bs[c + 3][r + 64] = b1.w;
        __syncthreads();
#pragma unroll
        for (int k = 0; k < 16; k++) {
            float4 aa0 = *(const float4*)&As[k][ty * 8];
            float4 aa1 = *(const float4*)&As[k][ty * 8 + 4];
            float4 bb0 = *(const float4*)&Bs[k][tx * 8];
            float4 bb1 = *(const float4*)&Bs[k][tx * 8 + 4];
            float a[8] = {aa0.x, aa0.y, aa0.z, aa0.w, aa1.x, aa1.y, aa1.z, aa1.w};
            float b[8] = {bb0.x, bb0.y, bb0.z, bb0.w, bb1.x, bb1.y, bb1.z, bb1.w};
#pragma unroll
            for (int i = 0; i < 8; i++)
#pragma unroll
                for (int j = 0; j < 8; j++) acc[i][j] = fmaf(a[i], b[j], acc[i][j]);
        }
        __syncthreads();
    }

#pragma unroll
    for (int i = 0; i < 8; i++) {
        const int m = m0 + ty * 8 + i;
#pragma unroll
        for (int j = 0; j < 8; j++) {
            const int n = n0 + tx * 8 + j;
            C[(size_t)m * N + n] = acc[i][j] + bias[n];
        }
    }
}

// ---------------------------------------------------------------------------
// K3: GRU scan, round 3.  grid=2, 512 threads (8 waves, 2 waves/SIMD =>
//     256-VGPR budget so 192 weight regs stay architectural).
//     Quad (4 lanes) owns TWO hidden dims: qA=quad, qB=quad+128, all 3 gates.
//     Lane l covers k in [64l, 64l+64).  192 v_dot2 per thread per step; each
//     h-chunk ds_read_b128 feeds 6 accumulators (halves LDS instr count vs r2).
//     Gate nonlinearity split across lanes: l==0 does qA, l==1 does qB.
// ---------------------------------------------------------------------------
#define HB_STRIDE 72   // 64 f16 payload + 8 f16 pad = 144 B (conflict-free)

__global__ __launch_bounds__(512, 2) void gru_scan_kernel(
    const float* __restrict__ whh_d, const float* __restrict__ whh_p,
    const float* __restrict__ bhh_d, const float* __restrict__ bhh_p,
    const float* __restrict__ gi_d, const float* __restrict__ gi_p,
    float* __restrict__ patient)
{
    const float* whh = blockIdx.x ? whh_p : whh_d;
    const float* bhh = blockIdx.x ? bhh_p : bhh_d;
    const float* gi  = blockIdx.x ? gi_p  : gi_d;
    const int col_off = blockIdx.x ? H_DIM : 0;

    const int tid = threadIdx.x;
    const int quad = tid >> 2;          // [0,128)
    const int l = tid & 3;
    const int qA = quad;
    const int qB = quad + 128;

    // --- weights: w[j][g][i] = k-dims (64l+2i, 64l+2i+1) of row g*256+q_j ---
    h2 w[2][3][32];
#pragma unroll
    for (int j = 0; j < 2; j++) {
        const int q = j ? qB : qA;
#pragma unroll
        for (int g = 0; g < 3; g++) {
            const float4* p = (const float4*)(whh + (size_t)(g * 256 + q) * H_DIM + l * 64);
#pragma unroll
            for (int i = 0; i < 16; i++) {
                float4 f = p[i];
                h2 v0; v0.x = (_Float16)f.x; v0.y = (_Float16)f.y;
                h2 v1; v1.x = (_Float16)f.z; v1.y = (_Float16)f.w;
                w[j][g][2 * i] = v0;
                w[j][g][2 * i + 1] = v1;
            }
        }
    }

    // per-lane selections: lane 0 -> qA, lane 1 -> qB (lanes 2,3 idle in gates)
    const int myq = (l == 1) ? qB : qA;
    const float bs0 = bhh[myq], bs1 = bhh[256 + myq], bs2 = bhh[512 + myq];

    __shared__ __align__(16) _Float16 hb[2][4 * HB_STRIDE];
    if (tid < 4 * HB_STRIDE) { hb[0][tid] = (_Float16)0.f; }

    float h = 0.f, g0 = 0.f, g1 = 0.f, g2 = 0.f;
    if (l < 2) { g0 = gi[myq]; g1 = gi[256 + myq]; g2 = gi[512 + myq]; }
    const int wchunk = myq >> 6;            // 0..3
    const int woff = (myq & 63);
    __syncthreads();

    for (int t = 0; t < T_SEQ; t++) {
        const uint4* hp = (const uint4*)(&hb[t & 1][l * HB_STRIDE]);
        float aA0 = 0.f, aA1 = 0.f, aA2 = 0.f;
        float aB0 = 0.f, aB1 = 0.f, aB2 = 0.f;
#pragma unroll
        for (int cI = 0; cI < 8; cI++) {
            const uint4 U = hp[cI];
            const h2 x0 = __builtin_bit_cast(h2, U.x);
            const h2 x1 = __builtin_bit_cast(h2, U.y);
            const h2 x2 = __builtin_bit_cast(h2, U.z);
            const h2 x3 = __builtin_bit_cast(h2, U.w);
            aA0 = fdot2(w[0][0][4 * cI + 0], x0, aA0);
            aA0 = fdot2(w[0][0][4 * cI + 1], x1, aA0);
            aA0 = fdot2(w[0][0][4 * cI + 2], x2, aA0);
            aA0 = fdot2(w[0][0][4 * cI + 3], x3, aA0);
            aA1 = fdot2(w[0][1][4 * cI + 0], x0, aA1);
            aA1 = fdot2(w[0][1][4 * cI + 1], x1, aA1);
            aA1 = fdot2(w[0][1][4 * cI + 2], x2, aA1);
            aA1 = fdot2(w[0][1][4 * cI + 3], x3, aA1);
            aA2 = fdot2(w[0][2][4 * cI + 0], x0, aA2);
            aA2 = fdot2(w[0][2][4 * cI + 1], x1, aA2);
            aA2 = fdot2(w[0][2][4 * cI + 2], x2, aA2);
            aA2 = fdot2(w[0][2][4 * cI + 3], x3, aA2);
            aB0 = fdot2(w[1][0][4 * cI + 0], x0, aB0);
            aB0 = fdot2(w[1][0][4 * cI + 1], x1, aB0);
            aB0 = fdot2(w[1][0][4 * cI + 2], x2, aB0);
            aB0 = fdot2(w[1][0][4 * cI + 3], x3, aB0);
            aB1 = fdot2(w[1][1][4 * cI + 0], x0, aB1);
            aB1 = fdot2(w[1][1][4 * cI + 1], x1, aB1);
            aB1 = fdot2(w[1][1][4 * cI + 2], x2, aB1);
            aB1 = fdot2(w[1][1][4 * cI + 3], x3, aB1);
            aB2 = fdot2(w[1][2][4 * cI + 0], x0, aB2);
            aB2 = fdot2(w[1][2][4 * cI + 1], x1, aB2);
            aB2 = fdot2(w[1][2][4 * cI + 2], x2, aB2);
            aB2 = fdot2(w[1][2][4 * cI + 3], x3, aB2);
        }
        // quad reductions (all lanes end up with the totals)
        aA0 = quad_sum(aA0); aA1 = quad_sum(aA1); aA2 = quad_sum(aA2);
        aB0 = quad_sum(aB0); aB1 = quad_sum(aB1); aB2 = quad_sum(aB2);

        if (l < 2) {
            const float a0 = (l == 0) ? aA0 : aB0;
            const float a1 = (l == 0) ? aA1 : aB1;
            const float a2 = (l == 0) ? aA2 : aB2;
            const float xr = g0 + a0 + bs0;
            const float xz = g1 + a1 + bs1;
            const float r = fast_rcp(1.f + __expf(-xr));
            const float z = fast_rcp(1.f + __expf(-xz));
            float xn = g2 + r * (a2 + bs2);
            xn = fminf(fmaxf(xn, -15.f), 15.f);
            const float e2 = __expf(2.f * xn);
            const float n = (e2 - 1.f) * fast_rcp(e2 + 1.f);
            h = (1.f - z) * n + z * h;
            hb[(t + 1) & 1][wchunk * HB_STRIDE + woff] = (_Float16)h;
            patient[(size_t)t * 512 + col_off + myq] = h;
            const int tn = (t < T_SEQ - 1) ? (t + 1) : t;   // prefetch next gi
            g0 = gi[(size_t)tn * G3 + myq];
            g1 = gi[(size_t)tn * G3 + 256 + myq];
            g2 = gi[(size_t)tn * G3 + 512 + myq];
        }
        __syncthreads();
    }
}

// ---------------------------------------------------------------------------
// K4: queries = relu(patient) @ w_lin^T + b_lin, scattered into d_out.
// ---------------------------------------------------------------------------
__global__ __launch_bounds__(256) void gemm_fin_kernel(
    const float* __restrict__ patient, const float* __restrict__ w_lin,
    const float* __restrict__ b_lin, float* __restrict__ out)
{
    const int K = 512, N = H_DIM;

    __shared__ float As[16][132];
    __shared__ float Bs[16][132];

    const int tid = threadIdx.x;
    const int tx = tid & 15, ty = tid >> 4;
    const int m0 = blockIdx.x * 128, n0 = blockIdx.y * 128;
    const int r = tid >> 2;
    const int c = (tid & 3) << 2;

    float acc[8][8];
#pragma unroll
    for (int i = 0; i < 8; i++)
#pragma unroll
        for (int j = 0; j < 8; j++) acc[i][j] = 0.f;

    for (int k0 = 0; k0 < K; k0 += 16) {
        float4 a0 = *(const float4*)&patient[(size_t)(m0 + r) * K + k0 + c];
        float4 a1 = *(const float4*)&patient[(size_t)(m0 + r + 64) * K + k0 + c];
        float4 b0 = *(const float4*)&w_lin[(size_t)(n0 + r) * K + k0 + c];
        float4 b1 = *(const float4*)&w_lin[(size_t)(n0 + r + 64) * K + k0 + c];
        a0.x = fmaxf(a0.x, 0.f); a0.y = fmaxf(a0.y, 0.f); a0.z = fmaxf(a0.z, 0.f); a0.w = fmaxf(a0.w, 0.f);
        a1.x = fmaxf(a1.x, 0.f); a1.y = fmaxf(a1.y, 0.f); a1.z = fmaxf(a1.z, 0.f); a1.w = fmaxf(a1.w, 0.f);
        As[c + 0][r] = a0.x; As[c + 1][r] = a0.y; As[c + 2][r] = a0.z; As[c + 3][r] = a0.w;
        As[c + 0][r + 64] = a1.x; As[c + 1][r + 64] = a1.y; As[c + 2][r + 64] = a1.z; As[c + 3][r + 64] = a1.w;
        Bs[c + 0][r] = b0.x; Bs[c + 1][r] = b0.y; Bs[c + 2][r] = b0.z; Bs[c + 3][r] = b0.w;
        Bs[c + 0][r + 64] = b1.x; Bs[c + 1][r + 64] = b1.y; Bs[c + 2][r + 64] = b1.z; Bs[c + 3][r + 64] = b1.w;
        __syncthreads();
#pragma unroll
        for (int k = 0; k < 16; k++) {
            float4 aa0 = *(const float4*)&As[k][ty * 8];
            float4 aa1 = *(const float4*)&As[k][ty * 8 + 4];
            float4 bb0 = *(const float4*)&Bs[k][tx * 8];
            float4 bb1 = *(const float4*)&Bs[k][tx * 8 + 4];
            float a[8] = {aa0.x, aa0.y, aa0.z, aa0.w, aa1.x, aa1.y, aa1.z, aa1.w};
            float b[8] = {bb0.x, bb0.y, bb0.z, bb0.w, bb1.x, bb1.y, bb1.z, bb1.w};
#pragma unroll
            for (int i = 0; i < 8; i++)
#pragma unroll
                for (int j = 0; j < 8; j++) acc[i][j] = fmaf(a[i], b[j], acc[i][j]);
        }
        __syncthreads();
    }

#pragma unroll
    for (int i = 0; i < 8; i++) {
        const int m = m0 + ty * 8 + i;
#pragma unroll
        for (int j = 0; j < 8; j++) {
            const int n = n0 + tx * 8 + j;
            const float v = acc[i][j] + b_lin[n];
            if (m == T_SEQ - 1) out[n] = v;                       // query
            else out[KEYS_OFF + (size_t)m * H_DIM + n] = v;       // memory_keys
        }
    }
}

// ---------------------------------------------------------------------------
extern "C" void kernel_launch(void* const* d_in, const int* in_sizes, int n_in,
                              void* d_out, int out_size, void* d_ws, size_t ws_size,
                              hipStream_t stream)
{
    const float* emb_diag = (const float*)d_in[0];
    // d_in[1] (emb_proc) is unused by the reference.
    const float* wih_d = (const float*)d_in[2];
    const float* whh_d = (const float*)d_in[3];
    const float* bih_d = (const float*)d_in[4];
    const float* bhh_d = (const float*)d_in[5];
    const float* wih_p = (const float*)d_in[6];
    const float* whh_p = (const float*)d_in[7];
    const float* bih_p = (const float*)d_in[8];
    const float* bhh_p = (const float*)d_in[9];
    const float* w_lin = (const float*)d_in[10];
    const float* b_lin = (const float*)d_in[11];
    const int* dcodes = (const int*)d_in[12];
    const int* pcodes = (const int*)d_in[13];
    const int* med    = (const int*)d_in[14];

    float* out = (float*)d_out;
    float* ws  = (float*)d_ws;

    float* seq_d   = ws + WS_SEQ_D;
    float* seq_p   = ws + WS_SEQ_P;
    float* gi_d    = ws + WS_GI_D;
    float* gi_p    = ws + WS_GI_P;
    float* patient = ws + WS_PATIENT;

    gather_mean_kernel<<<T_SEQ, 256, 0, stream>>>(
        emb_diag, dcodes, pcodes, med, seq_d, seq_p, out + MED_OFF);

    gemm_gi_kernel<<<dim3(32, 6, 2), 256, 0, stream>>>(
        seq_d, seq_p, wih_d, wih_p, bih_d, bih_p, gi_d, gi_p);

    gru_scan_kernel<<<2, 512, 0, stream>>>(
        whh_d, whh_p, bhh_d, bhh_p, gi_d, gi_p, patient);

    gemm_fin_kernel<<<dim3(32, 2, 1), 256, 0, stream>>>(
        patient, w_lin, b_lin, out);
}